// Round 11
// baseline (69.992 us; speedup 1.0000x reference)
//
#include <hip/hip_runtime.h>

#define B_ 8
#define T_ 256
#define U_ 64
#define U1_ 65
#define V_ 512
#define NDIAGP_ 336   // padded diagonal count (stage over-read stays in-bounds)
#define NT_ 4         // t-rows per k_logprobs block
#define CH_ 64        // diagonals per k_alpha chunk
#define NCH_ 5        // chunks cover d = 1..320 (d=320 fully masked)
#define LBBL_ 4352    // floats per BL LDS buffer (17*256 >= 64 rows * 65)
#define LBEM_ 4096    // floats per EM LDS buffer (16*256 = 64 rows * 64)

#define LOG2E_ 1.4426950408889634f
#define LN2_   0.6931471805599453f

#if __has_builtin(__builtin_amdgcn_exp2f)
#define EXP2(x) __builtin_amdgcn_exp2f(x)
#else
#define EXP2(x) exp2f(x)
#endif

// ---------------------------------------------------------------------------
// Kernel 0: edec = exp(dec) (float4); thread 0 also zeroes the output scalar.
// ---------------------------------------------------------------------------
__global__ __launch_bounds__(256) void k_exp(const float* __restrict__ x,
                                             float* __restrict__ y, int n4,
                                             float* __restrict__ out)
{
    int i = blockIdx.x * blockDim.x + threadIdx.x;
    if (i == 0) out[0] = 0.0f;
    if (i < n4) {
        float4 v = ((const float4*)x)[i];
        float4 r;
        r.x = __expf(v.x); r.y = __expf(v.y);
        r.z = __expf(v.z); r.w = __expf(v.w);
        ((float4*)y)[i] = r;
    }
}

// ---------------------------------------------------------------------------
// Kernel 1: block = (b, group of 4 t's). lse2[u] = log2( exp(enc_row) . edec_row[u] ).
// Diagonal-major log2-domain outputs:
//   BLD[b][t+u][u]  (stride 65) = (enc[0]+dec[u][0])*log2e     - lse2
//   EMD[b][t+u][u]  (stride 64) = (enc[tgt]+dec[u][tgt])*log2e - lse2
// ---------------------------------------------------------------------------
__global__ __launch_bounds__(256) void k_logprobs(
    const float* __restrict__ enc, const float* __restrict__ dec,
    const float* __restrict__ edec, const int* __restrict__ targets,
    float* __restrict__ BLD, float* __restrict__ EMD)
{
    const int blk  = blockIdx.x;           // 0 .. B_*T_/NT_ - 1
    const int b    = blk % B_;
    const int tg   = blk / B_;
    const int t0   = tg * NT_;
    const int wave = threadIdx.x >> 6;
    const int lane = threadIdx.x & 63;

    float4 xe0[NT_], xe1[NT_];
    #pragma unroll
    for (int j = 0; j < NT_; ++j) {
        const float* erow = enc + (size_t)(b * T_ + t0 + j) * V_;
        float4 e0 = *(const float4*)(erow + lane * 4);
        float4 e1 = *(const float4*)(erow + 256 + lane * 4);
        xe0[j].x = __expf(e0.x); xe0[j].y = __expf(e0.y);
        xe0[j].z = __expf(e0.z); xe0[j].w = __expf(e0.w);
        xe1[j].x = __expf(e1.x); xe1[j].y = __expf(e1.y);
        xe1[j].z = __expf(e1.z); xe1[j].w = __expf(e1.w);
    }

    for (int u = wave; u <= U_; u += 4) {
        const float* xdrow = edec + (size_t)(b * U1_ + u) * V_;
        float4 d0 = *(const float4*)(xdrow + lane * 4);
        float4 d1 = *(const float4*)(xdrow + 256 + lane * 4);

        float s[NT_];
        #pragma unroll
        for (int j = 0; j < NT_; ++j) {
            float sA = xe0[j].x * d0.x;
            float sB = xe1[j].x * d1.x;
            sA = fmaf(xe0[j].y, d0.y, sA);  sB = fmaf(xe1[j].y, d1.y, sB);
            sA = fmaf(xe0[j].z, d0.z, sA);  sB = fmaf(xe1[j].z, d1.z, sB);
            sA = fmaf(xe0[j].w, d0.w, sA);  sB = fmaf(xe1[j].w, d1.w, sB);
            s[j] = sA + sB;
        }

        #pragma unroll
        for (int off = 32; off > 0; off >>= 1) {
            #pragma unroll
            for (int j = 0; j < NT_; ++j)
                s[j] += __shfl_xor(s[j], off, 64);
        }

        if (lane == 0) {
            const float* dr = dec + (size_t)(b * U1_ + u) * V_;
            const float d_blank = dr[0];
            int   tgt = 0;
            float d_tgt = 0.0f;
            if (u < U_) { tgt = targets[b * U_ + u]; d_tgt = dr[tgt]; }
            #pragma unroll
            for (int j = 0; j < NT_; ++j) {
                const int t  = t0 + j;
                const int dg = t + u;
                const float lse2 = log2f(s[j]);
                const float* er = enc + (size_t)(b * T_ + t) * V_;
                BLD[((size_t)b * NDIAGP_ + dg) * U1_ + u] =
                    (er[0] + d_blank) * LOG2E_ - lse2;
                if (u < U_)
                    EMD[((size_t)b * NDIAGP_ + dg) * U_ + u] =
                        (er[tgt] + d_tgt) * LOG2E_ - lse2;
            }
        }
    }
}

// ---------------------------------------------------------------------------
// Kernel 2: alpha recursion in LINEAR domain relative to a log2 reference R,
// renormalized every 8 diagonals by the exact power-of-2 wave max (DPP
// reduce, no LDS). Lane l holds r = 2^(alpha[u=l+1] - R); r0 tracks the
// u=0 column. Waves 1-3 stage chunks via global_load_lds; wave 0 computes.
// ---------------------------------------------------------------------------
__device__ __forceinline__ float wshr1(float x) {
    // DPP wave_shr:1 (0x138): lane i <- lane i-1, lane 0 <- 0 (bound_ctrl)
    return __int_as_float(__builtin_amdgcn_update_dpp(
        0, __float_as_int(x), 0x138, 0xf, 0xf, true));
}
template <int CTRL>
__device__ __forceinline__ float dppmax(float x) {
    // invalid-source lanes get 0; r >= 0 so max unaffected
    return fmaxf(x, __int_as_float(__builtin_amdgcn_update_dpp(
        0, __float_as_int(x), CTRL, 0xf, 0xf, false)));
}
__device__ __forceinline__ float wave_max64(float x) {
    x = dppmax<0x111>(x);  // row_shr:1
    x = dppmax<0x112>(x);  // row_shr:2
    x = dppmax<0x114>(x);  // row_shr:4
    x = dppmax<0x118>(x);  // row_shr:8
    x = dppmax<0x142>(x);  // row_bcast:15
    x = dppmax<0x143>(x);  // row_bcast:31
    return __int_as_float(__builtin_amdgcn_readlane(__float_as_int(x), 63));
}

#define STAGE(c_) do {                                                          \
    if (wave > 0) {                                                             \
        const float* gbl = BLb + (size_t)(c_) * CH_ * U1_;                      \
        const float* gem = EMb + (size_t)(c_) * CH_ * U_;                       \
        float* lbl_ = sBL[(c_) & 1];                                            \
        float* lem_ = sEM[(c_) & 1];                                            \
        for (int i = wave - 1; i < 17; i += 3)                                  \
            __builtin_amdgcn_global_load_lds(                                   \
                (const __attribute__((address_space(1))) void*)(gbl + i * 256 + lane * 4), \
                (__attribute__((address_space(3))) void*)(lbl_ + i * 256), 16, 0, 0);      \
        for (int i = wave - 1; i < 16; i += 3)                                  \
            __builtin_amdgcn_global_load_lds(                                   \
                (const __attribute__((address_space(1))) void*)(gem + i * 256 + lane * 4), \
                (__attribute__((address_space(3))) void*)(lem_ + i * 256), 16, 0, 0);      \
    }                                                                           \
} while (0)

// relative row sj = (d-1) - d0; recursion at diag d reads diag d-1.
// pc: reference column (col 0 chunks 0-3; staircase col sj+1 chunk 4).
// pbv = 2^(blank[t-1][u]-pc), pev = 2^(emit[t][u-1]-pc), computed off-chain.
// fminf clamp: unwritten/poisoned cells (incl. NaN) -> finite; those lanes
// have r==0 so the bogus factor is annihilated (no 0*inf NaN).
// Chunk-4 mask: lanes l<=sj are dead (t>255) -> force factors to 0.
#define LOADL(PBV, PEV, PC, g_, UM_) do {                                       \
    _Pragma("unroll")                                                           \
    for (int j = 0; j < 8; ++j) {                                               \
        const int sj = 8 * (g_) + j;                                            \
        const float pc = lbl[sj * U1_ + ((UM_) ? (sj + 1) : 0)];                \
        float vb = fminf(lbl[sj * U1_ + lane + 1] - pc, 126.0f);                \
        float ve = fminf(lem[sj * U_ + lane] - pc, 126.0f);                     \
        if (UM_) {                                                              \
            vb = (lane <= sj) ? -200.0f : vb;                                   \
            ve = (lane <= sj) ? -200.0f : ve;                                   \
        }                                                                       \
        PBV[j] = EXP2(vb);                                                      \
        PEV[j] = EXP2(ve);                                                      \
        PC[j]  = pc;                                                            \
    }                                                                           \
} while (0)

#define COMPL(PBV, PEV, PC, g_) do {                                            \
    _Pragma("unroll")                                                           \
    for (int j = 0; j < 8; ++j) {                                               \
        const int d = d0 + 8 * (g_) + j + 1;                                    \
        float sr = wshr1(r);                                                    \
        sr = (lane == 0) ? r0 : sr;            /* left nbr of u=1 is col 0 */   \
        r = fmaf(sr, PEV[j], r * PBV[j]);                                       \
        if (d == dstar && lane == tl - 1)      /* uniform d-check, rare */      \
            atomicAdd(out, -(Rc + PC[j] + log2f(r) + fblank) * (LN2_ / B_));    \
        if (tl == 0 && d == il && lane == 0)   /* answer on the u=0 column */   \
            atomicAdd(out, -(Rc + log2f(r0) + fblank) * (LN2_ / B_));           \
        Rc += PC[j];                                                            \
    }                                                                           \
    /* renormalize: scale by exact 2^-e so max r ~ 1..2 */                      \
    {                                                                           \
        float m = wave_max64(r);                                                \
        int mb = __float_as_int(m);                                             \
        if (mb >= 0x00800000) {                /* m normal positive */          \
            int e = (mb >> 23) - 127;                                           \
            if (e != 0) {                                                       \
                float sc = __int_as_float((127 - e) << 23);                     \
                r *= sc;  r0 *= sc;  Rc += (float)e;                            \
            }                                                                   \
        }                                                                       \
    }                                                                           \
} while (0)

#define CHUNK_BODY(c_, UM_) do {                                                \
    const float* lbl = sBL[(c_) & 1];                                           \
    const float* lem = sEM[(c_) & 1];                                           \
    const int d0 = CH_ * (c_);                                                  \
    float pbA[8], peA[8], pcA[8];                                               \
    float pbB[8], peB[8], pcB[8];                                               \
    LOADL(pbA, peA, pcA, 0, UM_);                                               \
    for (int g = 0; g < 8; g += 2) {                                            \
        LOADL(pbB, peB, pcB, g + 1, UM_);                                       \
        COMPL(pbA, peA, pcA, g);                                                \
        if (g + 2 < 8) LOADL(pbA, peA, pcA, g + 2, UM_);                        \
        COMPL(pbB, peB, pcB, g + 1);                                            \
    }                                                                           \
} while (0)

__global__ __launch_bounds__(256) void k_alpha(
    const float* __restrict__ BLD, const float* __restrict__ EMD,
    const int* __restrict__ il_, const int* __restrict__ tl_,
    float* __restrict__ out)
{
    __shared__ __align__(16) float sBL[2][LBBL_];
    __shared__ __align__(16) float sEM[2][LBEM_];

    const int b    = blockIdx.x;
    const int wave = threadIdx.x >> 6;
    const int lane = threadIdx.x & 63;
    const int il   = il_[b];
    const int tl   = tl_[b];
    const int dstar = il - 1 + tl;
    const float* BLb = BLD + (size_t)b * NDIAGP_ * U1_;
    const float* EMb = EMD + (size_t)b * NDIAGP_ * U_;
    const float fblank = BLb[(size_t)dstar * U1_ + tl];

    float r  = 0.0f;   // 2^(alpha[u=lane+1] - R); 0 = not-yet-reachable
    float r0 = 1.0f;   // 2^(alpha[u=0] - R) (wave-uniform)
    float Rc = 0.0f;   // log2 reference R_{d-1} (wave-uniform)

    STAGE(0);
    __syncthreads();

    for (int c = 0; c < 4; ++c) {
        STAGE(c + 1);
        if (wave == 0) { CHUNK_BODY(c, 0); }
        __syncthreads();   // publishes chunk c+1, drains staging loads
    }
    // chunk 4 (d = 257..320): col 0 gone; staircase reference + dead-lane mask
    if (wave == 0) { CHUNK_BODY(4, 1); }
}

extern "C" void kernel_launch(void* const* d_in, const int* in_sizes, int n_in,
                              void* d_out, int out_size, void* d_ws, size_t ws_size,
                              hipStream_t stream)
{
    const float* enc     = (const float*)d_in[0];
    const float* dec     = (const float*)d_in[1];
    const int*   targets = (const int*)d_in[2];
    const int*   il      = (const int*)d_in[3];
    const int*   tl      = (const int*)d_in[4];
    float*       out     = (float*)d_out;

    float* edec = (float*)d_ws;                           // B*U1*V
    float* BLD  = edec + (size_t)B_ * U1_ * V_;           // B*NDIAGP*U1
    float* EMD  = BLD  + (size_t)B_ * NDIAGP_ * U1_;      // B*NDIAGP*U_

    const int n4 = B_ * U1_ * V_ / 4;
    k_exp<<<(n4 + 255) / 256, 256, 0, stream>>>(dec, edec, n4, out);
    k_logprobs<<<B_ * T_ / NT_, 256, 0, stream>>>(enc, dec, edec, targets, BLD, EMD);
    k_alpha<<<B_, 256, 0, stream>>>(BLD, EMD, il, tl, out);
}

// Round 12
// 66.176 us; speedup vs baseline: 1.0577x; 1.0577x over previous
//
#include <hip/hip_runtime.h>

#define B_ 8
#define T_ 256
#define U_ 64
#define U1_ 65
#define V_ 512
#define NDIAGP_ 336   // padded diagonal count
#define NT_ 4         // t-rows per k_logprobs block
#define CH_ 64        // diagonals per k_alpha chunk

#define LOG2E_ 1.4426950408889634f
#define LN2_   0.6931471805599453f

#if __has_builtin(__builtin_amdgcn_exp2f)
#define EXP2(x) __builtin_amdgcn_exp2f(x)
#else
#define EXP2(x) exp2f(x)
#endif

// ---------------------------------------------------------------------------
// Kernel 0: edec = exp(dec) (float4); thread 0 also zeroes the output scalar.
// ---------------------------------------------------------------------------
__global__ __launch_bounds__(256) void k_exp(const float* __restrict__ x,
                                             float* __restrict__ y, int n4,
                                             float* __restrict__ out)
{
    int i = blockIdx.x * blockDim.x + threadIdx.x;
    if (i == 0) out[0] = 0.0f;
    if (i < n4) {
        float4 v = ((const float4*)x)[i];
        float4 r;
        r.x = __expf(v.x); r.y = __expf(v.y);
        r.z = __expf(v.z); r.w = __expf(v.w);
        ((float4*)y)[i] = r;
    }
}

// ---------------------------------------------------------------------------
// Kernel 1: block = (b, group of 4 t's). lse2[u] = log2( exp(enc_row) . edec_row[u] ).
// Diagonal-major log2-domain outputs:
//   BLD[b][t+u][u]  (stride 65) = (enc[0]+dec[u][0])*log2e     - lse2
//   EMD[b][t+u][u]  (stride 64) = (enc[tgt]+dec[u][tgt])*log2e - lse2
// ---------------------------------------------------------------------------
__global__ __launch_bounds__(256) void k_logprobs(
    const float* __restrict__ enc, const float* __restrict__ dec,
    const float* __restrict__ edec, const int* __restrict__ targets,
    float* __restrict__ BLD, float* __restrict__ EMD)
{
    const int blk  = blockIdx.x;           // 0 .. B_*T_/NT_ - 1
    const int b    = blk % B_;
    const int tg   = blk / B_;
    const int t0   = tg * NT_;
    const int wave = threadIdx.x >> 6;
    const int lane = threadIdx.x & 63;

    float4 xe0[NT_], xe1[NT_];
    #pragma unroll
    for (int j = 0; j < NT_; ++j) {
        const float* erow = enc + (size_t)(b * T_ + t0 + j) * V_;
        float4 e0 = *(const float4*)(erow + lane * 4);
        float4 e1 = *(const float4*)(erow + 256 + lane * 4);
        xe0[j].x = __expf(e0.x); xe0[j].y = __expf(e0.y);
        xe0[j].z = __expf(e0.z); xe0[j].w = __expf(e0.w);
        xe1[j].x = __expf(e1.x); xe1[j].y = __expf(e1.y);
        xe1[j].z = __expf(e1.z); xe1[j].w = __expf(e1.w);
    }

    for (int u = wave; u <= U_; u += 4) {
        const float* xdrow = edec + (size_t)(b * U1_ + u) * V_;
        float4 d0 = *(const float4*)(xdrow + lane * 4);
        float4 d1 = *(const float4*)(xdrow + 256 + lane * 4);

        float s[NT_];
        #pragma unroll
        for (int j = 0; j < NT_; ++j) {
            float sA = xe0[j].x * d0.x;
            float sB = xe1[j].x * d1.x;
            sA = fmaf(xe0[j].y, d0.y, sA);  sB = fmaf(xe1[j].y, d1.y, sB);
            sA = fmaf(xe0[j].z, d0.z, sA);  sB = fmaf(xe1[j].z, d1.z, sB);
            sA = fmaf(xe0[j].w, d0.w, sA);  sB = fmaf(xe1[j].w, d1.w, sB);
            s[j] = sA + sB;
        }

        #pragma unroll
        for (int off = 32; off > 0; off >>= 1) {
            #pragma unroll
            for (int j = 0; j < NT_; ++j)
                s[j] += __shfl_xor(s[j], off, 64);
        }

        if (lane == 0) {
            const float* dr = dec + (size_t)(b * U1_ + u) * V_;
            const float d_blank = dr[0];
            int   tgt = 0;
            float d_tgt = 0.0f;
            if (u < U_) { tgt = targets[b * U_ + u]; d_tgt = dr[tgt]; }
            #pragma unroll
            for (int j = 0; j < NT_; ++j) {
                const int t  = t0 + j;
                const int dg = t + u;
                const float lse2 = log2f(s[j]);
                const float* er = enc + (size_t)(b * T_ + t) * V_;
                BLD[((size_t)b * NDIAGP_ + dg) * U1_ + u] =
                    (er[0] + d_blank) * LOG2E_ - lse2;
                if (u < U_)
                    EMD[((size_t)b * NDIAGP_ + dg) * U_ + u] =
                        (er[tgt] + d_tgt) * LOG2E_ - lse2;
            }
        }
    }
}

// ---------------------------------------------------------------------------
// Kernel 2: alpha recursion, linear domain vs. log2 reference R (renormalized
// every 8 diagonals by the exact power-of-2 wave max). PRODUCER waves 1-3 do
// the per-element exp2 conversion + masking and write packed {pbv,pev} float2
// rows + pc scalars to LDS (double-buffered). CONSUMER wave 0's loop is just
// ds_read_b64 + dpp + cndmask + mul + fma per diagonal.
// ---------------------------------------------------------------------------
__device__ __forceinline__ float wshr1(float x) {
    // DPP wave_shr:1 (0x138): lane i <- lane i-1, lane 0 <- 0 (bound_ctrl)
    return __int_as_float(__builtin_amdgcn_update_dpp(
        0, __float_as_int(x), 0x138, 0xf, 0xf, true));
}
template <int CTRL>
__device__ __forceinline__ float dppmax(float x) {
    return fmaxf(x, __int_as_float(__builtin_amdgcn_update_dpp(
        0, __float_as_int(x), CTRL, 0xf, 0xf, false)));
}
__device__ __forceinline__ float wave_max64(float x) {
    x = dppmax<0x111>(x);  // row_shr:1
    x = dppmax<0x112>(x);  // row_shr:2
    x = dppmax<0x114>(x);  // row_shr:4
    x = dppmax<0x118>(x);  // row_shr:8
    x = dppmax<0x142>(x);  // row_bcast:15
    x = dppmax<0x143>(x);  // row_bcast:31
    return __int_as_float(__builtin_amdgcn_readlane(__float_as_int(x), 63));
}

// Producer: rows i of chunk c_ hold diag d0+i. pbv = 2^(BL[diag][l+1]-pc),
// pev = 2^(EM[diag][l]-pc). pc = BL[diag][0] (chunks 0-3) or the staircase
// cell BL[diag][i+1] (chunk 4, via readlane). Masks: chunk0 t==0 patch
// (lane==i -> pbv=0), chunk4 dead lanes (lane<=i -> both 0). Clamp keeps
// hole garbage (incl. NaN, 0xAA poison) finite; dead lanes annihilate it.
#define STAGE(c_) do {                                                          \
    if (wave > 0) {                                                             \
        float2* pv_ = sPV[(c_) & 1];                                            \
        float*  pc_ = sPC[(c_) & 1];                                            \
        const int d0_ = CH_ * (c_);                                             \
        for (int i = wave - 1; i < CH_; i += 3) {                               \
            const float bl = BLb[(size_t)(d0_ + i) * U1_ + lane + 1];           \
            const float em = EMb[(size_t)(d0_ + i) * U_ + lane];                \
            float pc;                                                           \
            if ((c_) == 4)                                                      \
                pc = __int_as_float(                                            \
                    __builtin_amdgcn_readlane(__float_as_int(bl), i));          \
            else                                                                \
                pc = BLb[(size_t)(d0_ + i) * U1_];                              \
            float vb = fminf(bl - pc, 126.0f);                                  \
            float ve = fminf(em - pc, 126.0f);                                  \
            if ((c_) == 0 && lane == i) vb = -200.0f;                           \
            if ((c_) == 4 && lane <= i) { vb = -200.0f; ve = -200.0f; }         \
            pv_[i * 64 + lane] = make_float2(EXP2(vb), EXP2(ve));               \
            pc_[i] = pc;                                                        \
        }                                                                       \
    }                                                                           \
} while (0)

#define LOADG(PV, PC, g_) do {                                                  \
    _Pragma("unroll")                                                           \
    for (int j = 0; j < 8; ++j) {                                               \
        PV[j] = pvb[(8 * (g_) + j) * 64 + lane];                                \
        PC[j] = pcb[8 * (g_) + j];                                              \
    }                                                                           \
} while (0)

#define COMPG(PV, PC, g_) do {                                                  \
    _Pragma("unroll")                                                           \
    for (int j = 0; j < 8; ++j) {                                               \
        const int d = d0 + 8 * (g_) + j + 1;                                    \
        float sr = wshr1(r);                                                    \
        sr = (lane == 0) ? r0 : sr;            /* left nbr of u=1 is col 0 */   \
        r = fmaf(sr, PV[j].y, r * PV[j].x);                                     \
        if (d == dstar && lane == tl - 1)      /* uniform d-check, rare */      \
            atomicAdd(out, -(Rc + PC[j] + log2f(r) + fblank) * (LN2_ / B_));    \
        if (tl == 0 && d == il && lane == 0)   /* answer on the u=0 column */   \
            atomicAdd(out, -(Rc + log2f(r0) + fblank) * (LN2_ / B_));           \
        Rc += PC[j];                                                            \
    }                                                                           \
    /* renormalize: scale by exact 2^-e so max r ~ 1..2 */                      \
    {                                                                           \
        float m = wave_max64(r);                                                \
        int mb = __float_as_int(m);                                             \
        if (mb >= 0x00800000) {                /* m normal positive */          \
            int e = (mb >> 23) - 127;                                           \
            if (e != 0) {                                                       \
                float sc = __int_as_float((127 - e) << 23);                     \
                r *= sc;  r0 *= sc;  Rc += (float)e;                            \
            }                                                                   \
        }                                                                       \
    }                                                                           \
} while (0)

#define CHUNK_BODY(c_) do {                                                     \
    const float2* pvb = sPV[(c_) & 1];                                          \
    const float*  pcb = sPC[(c_) & 1];                                          \
    const int d0 = CH_ * (c_);                                                  \
    float2 pvA[8], pvB[8];                                                      \
    float  pcA[8], pcB[8];                                                      \
    LOADG(pvA, pcA, 0);                                                         \
    for (int g = 0; g < 8; g += 2) {                                            \
        LOADG(pvB, pcB, g + 1);                                                 \
        COMPG(pvA, pcA, g);                                                     \
        if (g + 2 < 8) LOADG(pvA, pcA, g + 2);                                  \
        COMPG(pvB, pcB, g + 1);                                                 \
    }                                                                           \
} while (0)

__global__ __launch_bounds__(256) void k_alpha(
    const float* __restrict__ BLD, const float* __restrict__ EMD,
    const int* __restrict__ il_, const int* __restrict__ tl_,
    float* __restrict__ out)
{
    __shared__ __align__(16) float2 sPV[2][CH_ * 64];   // 64 KiB
    __shared__ float sPC[2][CH_];                       // 512 B

    const int b    = blockIdx.x;
    const int wave = threadIdx.x >> 6;
    const int lane = threadIdx.x & 63;
    const int il   = il_[b];
    const int tl   = tl_[b];
    const int dstar = il - 1 + tl;
    const float* BLb = BLD + (size_t)b * NDIAGP_ * U1_;
    const float* EMb = EMD + (size_t)b * NDIAGP_ * U_;
    const float fblank = BLb[(size_t)dstar * U1_ + tl];

    float r  = 0.0f;   // 2^(alpha[u=lane+1] - R); 0 = not-yet-reachable
    float r0 = 1.0f;   // 2^(alpha[u=0] - R) (wave-uniform; renorm-scaled)
    float Rc = 0.0f;   // log2 reference R_{d-1} (wave-uniform)

    STAGE(0);
    __syncthreads();

    for (int c = 0; c < 4; ++c) {
        STAGE(c + 1);
        if (wave == 0) { CHUNK_BODY(c); }
        __syncthreads();   // publishes chunk c+1
    }
    // chunk 4 (d = 257..320): staircase reference, dead lanes pre-masked
    if (wave == 0) { CHUNK_BODY(4); }
}

extern "C" void kernel_launch(void* const* d_in, const int* in_sizes, int n_in,
                              void* d_out, int out_size, void* d_ws, size_t ws_size,
                              hipStream_t stream)
{
    const float* enc     = (const float*)d_in[0];
    const float* dec     = (const float*)d_in[1];
    const int*   targets = (const int*)d_in[2];
    const int*   il      = (const int*)d_in[3];
    const int*   tl      = (const int*)d_in[4];
    float*       out     = (float*)d_out;

    float* edec = (float*)d_ws;                           // B*U1*V
    float* BLD  = edec + (size_t)B_ * U1_ * V_;           // B*NDIAGP*U1
    float* EMD  = BLD  + (size_t)B_ * NDIAGP_ * U1_;      // B*NDIAGP*U_

    const int n4 = B_ * U1_ * V_ / 4;
    k_exp<<<(n4 + 255) / 256, 256, 0, stream>>>(dec, edec, n4, out);
    k_logprobs<<<B_ * T_ / NT_, 256, 0, stream>>>(enc, dec, edec, targets, BLD, EMD);
    k_alpha<<<B_, 256, 0, stream>>>(BLD, EMD, il, tl, out);
}

// Round 13
// 64.375 us; speedup vs baseline: 1.0873x; 1.0280x over previous
//
#include <hip/hip_runtime.h>

#define B_ 8
#define T_ 256
#define U_ 64
#define U1_ 65
#define V_ 512
#define NDIAGP_ 336   // padded diagonal count (GLDS over-read stays in-bounds)
#define NT_ 4         // t-rows per k_logprobs block
#define CH_ 64        // diagonals per k_alpha chunk

#define LOG2E_ 1.4426950408889634f
#define LN2_   0.6931471805599453f

#if __has_builtin(__builtin_amdgcn_exp2f)
#define EXP2(x) __builtin_amdgcn_exp2f(x)
#else
#define EXP2(x) exp2f(x)
#endif

// ---------------------------------------------------------------------------
// Kernel 0: edec = exp(dec) (float4); thread 0 also zeroes the output scalar.
// ---------------------------------------------------------------------------
__global__ __launch_bounds__(256) void k_exp(const float* __restrict__ x,
                                             float* __restrict__ y, int n4,
                                             float* __restrict__ out)
{
    int i = blockIdx.x * blockDim.x + threadIdx.x;
    if (i == 0) out[0] = 0.0f;
    if (i < n4) {
        float4 v = ((const float4*)x)[i];
        float4 r;
        r.x = __expf(v.x); r.y = __expf(v.y);
        r.z = __expf(v.z); r.w = __expf(v.w);
        ((float4*)y)[i] = r;
    }
}

// ---------------------------------------------------------------------------
// Kernel 1: block = (b, group of 4 t's). lse2[u] = log2( exp(enc_row) . edec_row[u] ).
// Diagonal-major log2-domain outputs:
//   BLD[b][t+u][u]  (stride 65) = (enc[0]+dec[u][0])*log2e     - lse2
//   EMD[b][t+u][u]  (stride 64) = (enc[tgt]+dec[u][tgt])*log2e - lse2
// ---------------------------------------------------------------------------
__global__ __launch_bounds__(256) void k_logprobs(
    const float* __restrict__ enc, const float* __restrict__ dec,
    const float* __restrict__ edec, const int* __restrict__ targets,
    float* __restrict__ BLD, float* __restrict__ EMD)
{
    const int blk  = blockIdx.x;           // 0 .. B_*T_/NT_ - 1
    const int b    = blk % B_;
    const int tg   = blk / B_;
    const int t0   = tg * NT_;
    const int wave = threadIdx.x >> 6;
    const int lane = threadIdx.x & 63;

    float4 xe0[NT_], xe1[NT_];
    #pragma unroll
    for (int j = 0; j < NT_; ++j) {
        const float* erow = enc + (size_t)(b * T_ + t0 + j) * V_;
        float4 e0 = *(const float4*)(erow + lane * 4);
        float4 e1 = *(const float4*)(erow + 256 + lane * 4);
        xe0[j].x = __expf(e0.x); xe0[j].y = __expf(e0.y);
        xe0[j].z = __expf(e0.z); xe0[j].w = __expf(e0.w);
        xe1[j].x = __expf(e1.x); xe1[j].y = __expf(e1.y);
        xe1[j].z = __expf(e1.z); xe1[j].w = __expf(e1.w);
    }

    for (int u = wave; u <= U_; u += 4) {
        const float* xdrow = edec + (size_t)(b * U1_ + u) * V_;
        float4 d0 = *(const float4*)(xdrow + lane * 4);
        float4 d1 = *(const float4*)(xdrow + 256 + lane * 4);

        float s[NT_];
        #pragma unroll
        for (int j = 0; j < NT_; ++j) {
            float sA = xe0[j].x * d0.x;
            float sB = xe1[j].x * d1.x;
            sA = fmaf(xe0[j].y, d0.y, sA);  sB = fmaf(xe1[j].y, d1.y, sB);
            sA = fmaf(xe0[j].z, d0.z, sA);  sB = fmaf(xe1[j].z, d1.z, sB);
            sA = fmaf(xe0[j].w, d0.w, sA);  sB = fmaf(xe1[j].w, d1.w, sB);
            s[j] = sA + sB;
        }

        #pragma unroll
        for (int off = 32; off > 0; off >>= 1) {
            #pragma unroll
            for (int j = 0; j < NT_; ++j)
                s[j] += __shfl_xor(s[j], off, 64);
        }

        if (lane == 0) {
            const float* dr = dec + (size_t)(b * U1_ + u) * V_;
            const float d_blank = dr[0];
            int   tgt = 0;
            float d_tgt = 0.0f;
            if (u < U_) { tgt = targets[b * U_ + u]; d_tgt = dr[tgt]; }
            #pragma unroll
            for (int j = 0; j < NT_; ++j) {
                const int t  = t0 + j;
                const int dg = t + u;
                const float lse2 = log2f(s[j]);
                const float* er = enc + (size_t)(b * T_ + t) * V_;
                BLD[((size_t)b * NDIAGP_ + dg) * U1_ + u] =
                    (er[0] + d_blank) * LOG2E_ - lse2;
                if (u < U_)
                    EMD[((size_t)b * NDIAGP_ + dg) * U_ + u] =
                        (er[tgt] + d_tgt) * LOG2E_ - lse2;
            }
        }
    }
}

// ---------------------------------------------------------------------------
// Kernel 2: alpha recursion, linear domain vs. log2 reference R (renorm every
// 8 diagonals, exact power-of-2). 3-stage pipeline per barrier interval:
//   waves 1-3: global_load_lds RAW chunk c+2 (fire-and-forget, drains at bar)
//   waves 1-3: convert RAW chunk c+1 (LDS->LDS, exp2 + masks, unrolled)
//   wave 0   : consume CONV chunk c (ds_read_b64 + dpp + fma per diagonal)
// ---------------------------------------------------------------------------
__device__ __forceinline__ float wshr1(float x) {
    // DPP wave_shr:1 (0x138): lane i <- lane i-1, lane 0 <- 0 (bound_ctrl)
    return __int_as_float(__builtin_amdgcn_update_dpp(
        0, __float_as_int(x), 0x138, 0xf, 0xf, true));
}
template <int CTRL>
__device__ __forceinline__ float dppmax(float x) {
    return fmaxf(x, __int_as_float(__builtin_amdgcn_update_dpp(
        0, __float_as_int(x), CTRL, 0xf, 0xf, false)));
}
__device__ __forceinline__ float wave_max64(float x) {
    x = dppmax<0x111>(x);  // row_shr:1
    x = dppmax<0x112>(x);  // row_shr:2
    x = dppmax<0x114>(x);  // row_shr:4
    x = dppmax<0x118>(x);  // row_shr:8
    x = dppmax<0x142>(x);  // row_bcast:15
    x = dppmax<0x143>(x);  // row_bcast:31
    return __int_as_float(__builtin_amdgcn_readlane(__float_as_int(x), 63));
}

// Stage raw chunk c_ (64 BL rows of 65 + 64 EM rows of 64) into raw buf c_&1.
#define GLDS(c_) do {                                                           \
    if (wave > 0) {                                                             \
        const float* gbl = BLb + (size_t)(c_) * CH_ * U1_;                      \
        const float* gem = EMb + (size_t)(c_) * CH_ * U_;                       \
        float* lbl_ = sRBL[(c_) & 1];                                           \
        float* lem_ = sREM[(c_) & 1];                                           \
        for (int i = wave - 1; i < 17; i += 3)                                  \
            __builtin_amdgcn_global_load_lds(                                   \
                (const __attribute__((address_space(1))) void*)(gbl + i * 256 + lane * 4), \
                (__attribute__((address_space(3))) void*)(lbl_ + i * 256), 16, 0, 0);      \
        for (int i = wave - 1; i < 16; i += 3)                                  \
            __builtin_amdgcn_global_load_lds(                                   \
                (const __attribute__((address_space(1))) void*)(gem + i * 256 + lane * 4), \
                (__attribute__((address_space(3))) void*)(lem_ + i * 256), 16, 0, 0);      \
    }                                                                           \
} while (0)

// Convert raw chunk c_ -> conv buffers. Row i holds raw diag d0+i, consumed
// at diag d = d0+i+1. pbv = 2^(BL[diag][l+1]-pc), pev = 2^(EM[diag][l]-pc).
// pc: col 0 (chunks 0-3) or staircase col i+1 (chunk 4, uniform LDS read).
// Masks: chunk0 t==0 patch (lane==i -> pbv=0); chunk4 dead lanes (lane<=i).
// fminf clamp keeps hole garbage finite (NaN -> 126); dead lanes have r==0.
#define CONV(c_) do {                                                           \
    if (wave > 0) {                                                             \
        const float* rbl = sRBL[(c_) & 1];                                      \
        const float* rem = sREM[(c_) & 1];                                      \
        float2* pv_ = sPV[(c_) & 1];                                            \
        float*  pc_ = sPC[(c_) & 1];                                            \
        _Pragma("unroll 4")                                                     \
        for (int i = wave - 1; i < CH_; i += 3) {                               \
            const float bl = rbl[i * U1_ + lane + 1];                           \
            const float em = rem[i * U_ + lane];                                \
            const float pc = ((c_) == 4) ? rbl[i * U1_ + i + 1]                 \
                                         : rbl[i * U1_];                        \
            float vb = fminf(bl - pc, 126.0f);                                  \
            float ve = fminf(em - pc, 126.0f);                                  \
            if ((c_) == 0 && lane == i) vb = -200.0f;                           \
            if ((c_) == 4 && lane <= i) { vb = -200.0f; ve = -200.0f; }         \
            pv_[i * 64 + lane] = make_float2(EXP2(vb), EXP2(ve));               \
            if (lane == 0) pc_[i] = pc;                                         \
        }                                                                       \
    }                                                                           \
} while (0)

#define LOADG(PV, PC, g_) do {                                                  \
    _Pragma("unroll")                                                           \
    for (int j = 0; j < 8; ++j) {                                               \
        PV[j] = pvb[(8 * (g_) + j) * 64 + lane];                                \
        PC[j] = pcb[8 * (g_) + j];                                              \
    }                                                                           \
} while (0)

#define COMPG(PV, PC, g_) do {                                                  \
    _Pragma("unroll")                                                           \
    for (int j = 0; j < 8; ++j) {                                               \
        const int d = d0 + 8 * (g_) + j + 1;                                    \
        float sr = wshr1(r);                                                    \
        sr = (lane == 0) ? r0 : sr;            /* left nbr of u=1 is col 0 */   \
        r = fmaf(sr, PV[j].y, r * PV[j].x);                                     \
        if (d == dstar && lane == tl - 1)      /* uniform d-check, rare */      \
            atomicAdd(out, -(Rc + PC[j] + log2f(r) + fblank) * (LN2_ / B_));    \
        if (tl == 0 && d == il && lane == 0)   /* answer on the u=0 column */   \
            atomicAdd(out, -(Rc + log2f(r0) + fblank) * (LN2_ / B_));           \
        Rc += PC[j];                                                            \
    }                                                                           \
    /* renormalize: scale by exact 2^-e so max r ~ 1..2 */                      \
    {                                                                           \
        float m = wave_max64(r);                                                \
        int mb = __float_as_int(m);                                             \
        if (mb >= 0x00800000) {                /* m normal positive */          \
            int e = (mb >> 23) - 127;                                           \
            if (e != 0) {                                                       \
                float sc = __int_as_float((127 - e) << 23);                     \
                r *= sc;  r0 *= sc;  Rc += (float)e;                            \
            }                                                                   \
        }                                                                       \
    }                                                                           \
} while (0)

#define CHUNK_BODY(c_) do {                                                     \
    const float2* pvb = sPV[(c_) & 1];                                          \
    const float*  pcb = sPC[(c_) & 1];                                          \
    const int d0 = CH_ * (c_);                                                  \
    float2 pvA[8], pvB[8];                                                      \
    float  pcA[8], pcB[8];                                                      \
    LOADG(pvA, pcA, 0);                                                         \
    for (int g = 0; g < 8; g += 2) {                                            \
        LOADG(pvB, pcB, g + 1);                                                 \
        COMPG(pvA, pcA, g);                                                     \
        if (g + 2 < 8) LOADG(pvA, pcA, g + 2);                                  \
        COMPG(pvB, pcB, g + 1);                                                 \
    }                                                                           \
} while (0)

__global__ __launch_bounds__(256) void k_alpha(
    const float* __restrict__ BLD, const float* __restrict__ EMD,
    const int* __restrict__ il_, const int* __restrict__ tl_,
    float* __restrict__ out)
{
    __shared__ __align__(16) float  sRBL[2][17 * 256];   // raw BL (34.0 KB)
    __shared__ __align__(16) float  sREM[2][16 * 256];   // raw EM (32.0 KB)
    __shared__ __align__(16) float2 sPV[2][CH_ * 64];    // converted (64 KB)
    __shared__ float sPC[2][CH_];                        // refs (512 B)

    const int b    = blockIdx.x;
    const int wave = threadIdx.x >> 6;
    const int lane = threadIdx.x & 63;
    const int il   = il_[b];
    const int tl   = tl_[b];
    const int dstar = il - 1 + tl;
    const float* BLb = BLD + (size_t)b * NDIAGP_ * U1_;
    const float* EMb = EMD + (size_t)b * NDIAGP_ * U_;
    const float fblank = BLb[(size_t)dstar * U1_ + tl];

    float r  = 0.0f;   // 2^(alpha[u=lane+1] - R); 0 = not-yet-reachable
    float r0 = 1.0f;   // 2^(alpha[u=0] - R) (wave-uniform; renorm-scaled)
    float Rc = 0.0f;   // log2 reference R_{d-1} (wave-uniform)

    GLDS(0);
    __syncthreads();           // raw0 ready
    GLDS(1);
    CONV(0);
    __syncthreads();           // conv0 + raw1 ready

    for (int c = 0; c < 5; ++c) {
        if (c + 2 <= 4) GLDS(c + 2);
        if (c + 1 <= 4) CONV(c + 1);
        if (wave == 0) { CHUNK_BODY(c); }
        __syncthreads();       // conv(c+1) + raw(c+2) ready
    }
}

extern "C" void kernel_launch(void* const* d_in, const int* in_sizes, int n_in,
                              void* d_out, int out_size, void* d_ws, size_t ws_size,
                              hipStream_t stream)
{
    const float* enc     = (const float*)d_in[0];
    const float* dec     = (const float*)d_in[1];
    const int*   targets = (const int*)d_in[2];
    const int*   il      = (const int*)d_in[3];
    const int*   tl      = (const int*)d_in[4];
    float*       out     = (float*)d_out;

    float* edec = (float*)d_ws;                           // B*U1*V
    float* BLD  = edec + (size_t)B_ * U1_ * V_;           // B*NDIAGP*U1
    float* EMD  = BLD  + (size_t)B_ * NDIAGP_ * U1_;      // B*NDIAGP*U_

    const int n4 = B_ * U1_ * V_ / 4;
    k_exp<<<(n4 + 255) / 256, 256, 0, stream>>>(dec, edec, n4, out);
    k_logprobs<<<B_ * T_ / NT_, 256, 0, stream>>>(enc, dec, edec, targets, BLD, EMD);
    k_alpha<<<B_, 256, 0, stream>>>(BLD, EMD, il, tl, out);
}

// Round 14
// 55.433 us; speedup vs baseline: 1.2626x; 1.1613x over previous
//
#include <hip/hip_runtime.h>

#define B_ 8
#define T_ 256
#define U_ 64
#define U1_ 65
#define V_ 512
#define NDIAGP_ 336   // padded diagonal count (GLDS over-read stays in-bounds)
#define NT_ 4         // t-rows per k_logprobs block
#define CH_ 64        // diagonals per k_alpha chunk

#define LOG2E_ 1.4426950408889634f
#define LN2_   0.6931471805599453f

#if __has_builtin(__builtin_amdgcn_exp2f)
#define EXP2(x) __builtin_amdgcn_exp2f(x)
#else
#define EXP2(x) exp2f(x)
#endif

// ---------------------------------------------------------------------------
// Kernel 0: edec = exp(dec) (float4); thread 0 also zeroes the output scalar.
// ---------------------------------------------------------------------------
__global__ __launch_bounds__(256) void k_exp(const float* __restrict__ x,
                                             float* __restrict__ y, int n4,
                                             float* __restrict__ out)
{
    int i = blockIdx.x * blockDim.x + threadIdx.x;
    if (i == 0) out[0] = 0.0f;
    if (i < n4) {
        float4 v = ((const float4*)x)[i];
        float4 r;
        r.x = __expf(v.x); r.y = __expf(v.y);
        r.z = __expf(v.z); r.w = __expf(v.w);
        ((float4*)y)[i] = r;
    }
}

// ---------------------------------------------------------------------------
// Kernel 1: block = (b, group of 4 t's). lse2[u] = log2( exp(enc_row) . edec_row[u] ).
// Diagonal-major log2-domain outputs:
//   BLD[b][t+u][u]  (stride 65) = (enc[0]+dec[u][0])*log2e     - lse2
//   EMD[b][t+u][u]  (stride 64) = (enc[tgt]+dec[u][tgt])*log2e - lse2
// ---------------------------------------------------------------------------
__global__ __launch_bounds__(256) void k_logprobs(
    const float* __restrict__ enc, const float* __restrict__ dec,
    const float* __restrict__ edec, const int* __restrict__ targets,
    float* __restrict__ BLD, float* __restrict__ EMD)
{
    const int blk  = blockIdx.x;           // 0 .. B_*T_/NT_ - 1
    const int b    = blk % B_;
    const int tg   = blk / B_;
    const int t0   = tg * NT_;
    const int wave = threadIdx.x >> 6;
    const int lane = threadIdx.x & 63;

    float4 xe0[NT_], xe1[NT_];
    #pragma unroll
    for (int j = 0; j < NT_; ++j) {
        const float* erow = enc + (size_t)(b * T_ + t0 + j) * V_;
        float4 e0 = *(const float4*)(erow + lane * 4);
        float4 e1 = *(const float4*)(erow + 256 + lane * 4);
        xe0[j].x = __expf(e0.x); xe0[j].y = __expf(e0.y);
        xe0[j].z = __expf(e0.z); xe0[j].w = __expf(e0.w);
        xe1[j].x = __expf(e1.x); xe1[j].y = __expf(e1.y);
        xe1[j].z = __expf(e1.z); xe1[j].w = __expf(e1.w);
    }

    for (int u = wave; u <= U_; u += 4) {
        const float* xdrow = edec + (size_t)(b * U1_ + u) * V_;
        float4 d0 = *(const float4*)(xdrow + lane * 4);
        float4 d1 = *(const float4*)(xdrow + 256 + lane * 4);

        float s[NT_];
        #pragma unroll
        for (int j = 0; j < NT_; ++j) {
            float sA = xe0[j].x * d0.x;
            float sB = xe1[j].x * d1.x;
            sA = fmaf(xe0[j].y, d0.y, sA);  sB = fmaf(xe1[j].y, d1.y, sB);
            sA = fmaf(xe0[j].z, d0.z, sA);  sB = fmaf(xe1[j].z, d1.z, sB);
            sA = fmaf(xe0[j].w, d0.w, sA);  sB = fmaf(xe1[j].w, d1.w, sB);
            s[j] = sA + sB;
        }

        #pragma unroll
        for (int off = 32; off > 0; off >>= 1) {
            #pragma unroll
            for (int j = 0; j < NT_; ++j)
                s[j] += __shfl_xor(s[j], off, 64);
        }

        if (lane == 0) {
            const float* dr = dec + (size_t)(b * U1_ + u) * V_;
            const float d_blank = dr[0];
            int   tgt = 0;
            float d_tgt = 0.0f;
            if (u < U_) { tgt = targets[b * U_ + u]; d_tgt = dr[tgt]; }
            #pragma unroll
            for (int j = 0; j < NT_; ++j) {
                const int t  = t0 + j;
                const int dg = t + u;
                const float lse2 = log2f(s[j]);
                const float* er = enc + (size_t)(b * T_ + t) * V_;
                BLD[((size_t)b * NDIAGP_ + dg) * U1_ + u] =
                    (er[0] + d_blank) * LOG2E_ - lse2;
                if (u < U_)
                    EMD[((size_t)b * NDIAGP_ + dg) * U_ + u] =
                        (er[tgt] + d_tgt) * LOG2E_ - lse2;
            }
        }
    }
}

// ---------------------------------------------------------------------------
// Kernel 2: alpha recursion, linear domain vs. log2 reference R (renorm every
// 8 diagonals, exact power-of-2, branchless). 3-stage pipeline per barrier:
//   waves 1-3: global_load_lds RAW chunk c+2 (fire-and-forget)
//   waves 1-3: convert RAW chunk c+1 (LDS->LDS, exp2 + masks)
//   wave 0   : consume CONV chunk c — per diagonal: ds_read + dpp + fma +
//              1 scalar compare + 2 cndmask (answer capture; NO branches).
// One atomicAdd at kernel end.
// ---------------------------------------------------------------------------
__device__ __forceinline__ float wshr1(float x) {
    // DPP wave_shr:1 (0x138): lane i <- lane i-1, lane 0 <- 0 (bound_ctrl)
    return __int_as_float(__builtin_amdgcn_update_dpp(
        0, __float_as_int(x), 0x138, 0xf, 0xf, true));
}
template <int CTRL>
__device__ __forceinline__ float dppmax(float x) {
    return fmaxf(x, __int_as_float(__builtin_amdgcn_update_dpp(
        0, __float_as_int(x), CTRL, 0xf, 0xf, false)));
}
__device__ __forceinline__ float wave_max64(float x) {
    x = dppmax<0x111>(x);  // row_shr:1
    x = dppmax<0x112>(x);  // row_shr:2
    x = dppmax<0x114>(x);  // row_shr:4
    x = dppmax<0x118>(x);  // row_shr:8
    x = dppmax<0x142>(x);  // row_bcast:15
    x = dppmax<0x143>(x);  // row_bcast:31
    return __int_as_float(__builtin_amdgcn_readlane(__float_as_int(x), 63));
}

// Stage raw chunk c_ (64 BL rows of 65 + 64 EM rows of 64) into raw buf c_&1.
#define GLDS(c_) do {                                                           \
    if (wave > 0) {                                                             \
        const float* gbl = BLb + (size_t)(c_) * CH_ * U1_;                      \
        const float* gem = EMb + (size_t)(c_) * CH_ * U_;                       \
        float* lbl_ = sRBL[(c_) & 1];                                           \
        float* lem_ = sREM[(c_) & 1];                                           \
        for (int i = wave - 1; i < 17; i += 3)                                  \
            __builtin_amdgcn_global_load_lds(                                   \
                (const __attribute__((address_space(1))) void*)(gbl + i * 256 + lane * 4), \
                (__attribute__((address_space(3))) void*)(lbl_ + i * 256), 16, 0, 0);      \
        for (int i = wave - 1; i < 16; i += 3)                                  \
            __builtin_amdgcn_global_load_lds(                                   \
                (const __attribute__((address_space(1))) void*)(gem + i * 256 + lane * 4), \
                (__attribute__((address_space(3))) void*)(lem_ + i * 256), 16, 0, 0);      \
    }                                                                           \
} while (0)

// Convert raw chunk c_ -> conv buffers (see R13 comments; unchanged).
#define CONV(c_) do {                                                           \
    if (wave > 0) {                                                             \
        const float* rbl = sRBL[(c_) & 1];                                      \
        const float* rem = sREM[(c_) & 1];                                      \
        float2* pv_ = sPV[(c_) & 1];                                            \
        float*  pc_ = sPC[(c_) & 1];                                            \
        _Pragma("unroll 4")                                                     \
        for (int i = wave - 1; i < CH_; i += 3) {                               \
            const float bl = rbl[i * U1_ + lane + 1];                           \
            const float em = rem[i * U_ + lane];                                \
            const float pc = ((c_) == 4) ? rbl[i * U1_ + i + 1]                 \
                                         : rbl[i * U1_];                        \
            float vb = fminf(bl - pc, 126.0f);                                  \
            float ve = fminf(em - pc, 126.0f);                                  \
            if ((c_) == 0 && lane == i) vb = -200.0f;                           \
            if ((c_) == 4 && lane <= i) { vb = -200.0f; ve = -200.0f; }         \
            pv_[i * 64 + lane] = make_float2(EXP2(vb), EXP2(ve));               \
            if (lane == 0) pc_[i] = pc;                                         \
        }                                                                       \
    }                                                                           \
} while (0)

#define LOADG(PV, PC, g_) do {                                                  \
    _Pragma("unroll")                                                           \
    for (int j = 0; j < 8; ++j) {                                               \
        PV[j] = pvb[(8 * (g_) + j) * 64 + lane];                                \
        PC[j] = pcb[8 * (g_) + j];                                              \
    }                                                                           \
} while (0)

// Branchless: capture (savedV, savedC) at d == cap_d; renorm without branch.
#define COMPG(PV, PC, g_) do {                                                  \
    _Pragma("unroll")                                                           \
    for (int j = 0; j < 8; ++j) {                                               \
        const int d = d0 + 8 * (g_) + j + 1;                                    \
        float sr = wshr1(r);                                                    \
        sr = lane0 ? r0 : sr;                  /* left nbr of u=1 is col 0 */   \
        r = fmaf(sr, PV[j].y, r * PV[j].x);                                     \
        const bool cap = (d == cap_d);                                          \
        savedV = cap ? (tlpos ? r : r0) : savedV;                               \
        savedC = cap ? (tlpos ? Rc + PC[j] : Rc) : savedC;                      \
        Rc += PC[j];                                                            \
    }                                                                           \
    /* renormalize: scale by exact 2^-e so max r ~ 1..2 (branchless) */         \
    {                                                                           \
        float m = wave_max64(r);                                                \
        int mb = __float_as_int(m);                                             \
        int e = (mb >> 23) - 127;                                               \
        e = (mb >= 0x00800000) ? e : 0;        /* zero/denorm -> skip */        \
        float sc = __int_as_float((127 - e) << 23);                             \
        r *= sc;  r0 *= sc;  Rc += (float)e;                                    \
    }                                                                           \
} while (0)

#define CHUNK_BODY(c_) do {                                                     \
    const float2* pvb = sPV[(c_) & 1];                                          \
    const float*  pcb = sPC[(c_) & 1];                                          \
    const int d0 = CH_ * (c_);                                                  \
    float2 pvA[8], pvB[8];                                                      \
    float  pcA[8], pcB[8];                                                      \
    LOADG(pvA, pcA, 0);                                                         \
    for (int g = 0; g < 8; g += 2) {                                            \
        LOADG(pvB, pcB, g + 1);                                                 \
        COMPG(pvA, pcA, g);                                                     \
        if (g + 2 < 8) LOADG(pvA, pcA, g + 2);                                  \
        COMPG(pvB, pcB, g + 1);                                                 \
    }                                                                           \
} while (0)

__global__ __launch_bounds__(256) void k_alpha(
    const float* __restrict__ BLD, const float* __restrict__ EMD,
    const int* __restrict__ il_, const int* __restrict__ tl_,
    float* __restrict__ out)
{
    __shared__ __align__(16) float  sRBL[2][17 * 256];   // raw BL (34.0 KB)
    __shared__ __align__(16) float  sREM[2][16 * 256];   // raw EM (32.0 KB)
    __shared__ __align__(16) float2 sPV[2][CH_ * 64];    // converted (64 KB)
    __shared__ float sPC[2][CH_];                        // refs (512 B)

    const int b    = blockIdx.x;
    const int wave = threadIdx.x >> 6;
    const int lane = threadIdx.x & 63;
    const int il   = il_[b];
    const int tl   = tl_[b];
    const int dstar = il - 1 + tl;
    const float* BLb = BLD + (size_t)b * NDIAGP_ * U1_;
    const float* EMb = EMD + (size_t)b * NDIAGP_ * U_;
    const float fblank = BLb[(size_t)dstar * U1_ + tl];

    const bool lane0 = (lane == 0);
    const bool tlpos = (tl > 0);
    const int  cap_d = tlpos ? dstar : il;   // capture diagonal (>= 1 always)

    float r  = 0.0f;   // 2^(alpha[u=lane+1] - R); 0 = not-yet-reachable
    float r0 = 1.0f;   // 2^(alpha[u=0] - R) (wave-uniform; renorm-scaled)
    float Rc = 0.0f;   // log2 reference R_{d-1} (wave-uniform)
    float savedV = 1.0f, savedC = 0.0f;   // captured answer pieces

    GLDS(0);
    __syncthreads();           // raw0 ready
    GLDS(1);
    CONV(0);
    __syncthreads();           // conv0 + raw1 ready

    for (int c = 0; c < 5; ++c) {
        if (c + 2 <= 4) GLDS(c + 2);
        if (c + 1 <= 4) CONV(c + 1);
        if (wave == 0) { CHUNK_BODY(c); }
        __syncthreads();       // conv(c+1) + raw(c+2) ready
    }

    if (wave == 0) {
        const int sl = tlpos ? (tl - 1) : 0;
        float sv = __int_as_float(
            __builtin_amdgcn_readlane(__float_as_int(savedV), sl));
        float sc = __int_as_float(
            __builtin_amdgcn_readlane(__float_as_int(savedC), 0));
        if (lane == 0)
            atomicAdd(out, -(sc + log2f(sv) + fblank) * (LN2_ / B_));
    }
}

extern "C" void kernel_launch(void* const* d_in, const int* in_sizes, int n_in,
                              void* d_out, int out_size, void* d_ws, size_t ws_size,
                              hipStream_t stream)
{
    const float* enc     = (const float*)d_in[0];
    const float* dec     = (const float*)d_in[1];
    const int*   targets = (const int*)d_in[2];
    const int*   il      = (const int*)d_in[3];
    const int*   tl      = (const int*)d_in[4];
    float*       out     = (float*)d_out;

    float* edec = (float*)d_ws;                           // B*U1*V
    float* BLD  = edec + (size_t)B_ * U1_ * V_;           // B*NDIAGP*U1
    float* EMD  = BLD  + (size_t)B_ * NDIAGP_ * U1_;      // B*NDIAGP*U_

    const int n4 = B_ * U1_ * V_ / 4;
    k_exp<<<(n4 + 255) / 256, 256, 0, stream>>>(dec, edec, n4, out);
    k_logprobs<<<B_ * T_ / NT_, 256, 0, stream>>>(enc, dec, edec, targets, BLD, EMD);
    k_alpha<<<B_, 256, 0, stream>>>(BLD, EMD, il, tl, out);
}